// Round 2
// baseline (999.062 us; speedup 1.0000x reference)
//
#include <hip/hip_runtime.h>
#include <hip/hip_fp16.h>

// ---------------------------------------------------------------------------
// VQFFN1: out = softmax(rmsnorm(x) @ rmsnorm(w)^T) @ w
//   x: [16384,1024] fp32   w: [4096,1024] fp32   out: [16384,1024] fp32
// Scores kept in fp32 (softmax is near-argmax; fp16 S storage breaks top-2
// gaps). GEMM1 uses compensated fp16: S = xh*wh + xl*wh + xh*wl (K'=3072).
// GEMM2 (P @ w) is plain fp16 MFMA (P in [0,1], error << threshold).
// M chunked 4 x 4096 so the fp32 S buffer is 64 MiB (ws total 152 MiB).
// ---------------------------------------------------------------------------

#define D_MODEL 1024
#define D_FF    4096
#define M_ROWS  16384
#define MC      4096

typedef _Float16 half8 __attribute__((ext_vector_type(8)));
typedef _Float16 half4 __attribute__((ext_vector_type(4)));
typedef float    floatx4 __attribute__((ext_vector_type(4)));

// async global->LDS, 16B/lane; LDS dst = wave-uniform base + lane*16 (m97)
__device__ __forceinline__ void gld_lds16(const void* g, void* l) {
  __builtin_amdgcn_global_load_lds(
      (const __attribute__((address_space(1))) void*)g,
      (__attribute__((address_space(3))) void*)l, 16, 0, 0);
}

// ---------------------------------------------------------------------------
// rmsnorm (fp32 in) + hi/lo fp16 split. One wave per row of 1024.
// ---------------------------------------------------------------------------
__global__ __launch_bounds__(256) void rmsnorm_split_kernel(
    const float* __restrict__ X, _Float16* __restrict__ XH,
    _Float16* __restrict__ XL) {
  const int lane = threadIdx.x & 63;
  const long row = (long)blockIdx.x * 4 + (threadIdx.x >> 6);
  const float* x = X + row * D_MODEL;
  float v[16];
  float ss = 0.f;
#pragma unroll
  for (int s = 0; s < 4; s++) {
    const float4 f = *(const float4*)(x + s * 256 + lane * 4);
    v[s * 4 + 0] = f.x; v[s * 4 + 1] = f.y;
    v[s * 4 + 2] = f.z; v[s * 4 + 3] = f.w;
    ss += f.x * f.x + f.y * f.y + f.z * f.z + f.w * f.w;
  }
#pragma unroll
  for (int off = 32; off >= 1; off >>= 1) ss += __shfl_xor(ss, off);
  const float inv = rsqrtf(ss * (1.0f / D_MODEL) + 1e-6f);
#pragma unroll
  for (int s = 0; s < 4; s++) {
    half4 h, l;
#pragma unroll
    for (int j = 0; j < 4; j++) {
      const float t = v[s * 4 + j] * inv;
      const _Float16 hi = (_Float16)t;
      h[j] = hi;
      l[j] = (_Float16)(t - (float)hi);
    }
    *(half4*)(XH + row * D_MODEL + s * 256 + lane * 4) = h;
    *(half4*)(XL + row * D_MODEL + s * 256 + lane * 4) = l;
  }
}

// ---------------------------------------------------------------------------
// transpose w [4096,1024] fp32 -> wT [1024,4096] fp16 (unnormalized, GEMM2 B)
// ---------------------------------------------------------------------------
__global__ __launch_bounds__(256) void transpose_kernel(
    const float* __restrict__ W, _Float16* __restrict__ WT) {
  __shared__ _Float16 tile[32][33];
  const int tx = threadIdx.x & 31;
  const int ty = threadIdx.x >> 5;  // 0..7
  const int d0 = blockIdx.x * 32;
  const int c0 = blockIdx.y * 32;
#pragma unroll
  for (int i = 0; i < 32; i += 8)
    tile[ty + i][tx] = (_Float16)W[(long)(c0 + ty + i) * D_MODEL + d0 + tx];
  __syncthreads();
#pragma unroll
  for (int i = 0; i < 32; i += 8)
    WT[(long)(d0 + ty + i) * D_FF + c0 + tx] = tile[tx][ty + i];
}

// ---------------------------------------------------------------------------
// GEMM1 (compensated): S[4096,4096] fp32 = sum over 48 K-tiles of 64:
//   seg0: XH*WH^T  seg1: XL*WH^T  seg2: XH*WL^T   (all row-major [rows,1024])
// m97 structure: 128x128 tile, 4 waves 2x2, 4x4 of 16x16x32 f16 MFMA, BK=64.
// ---------------------------------------------------------------------------
__global__ __launch_bounds__(256, 2) void gemm1_kernel(
    const _Float16* __restrict__ XH, const _Float16* __restrict__ XL,
    const _Float16* __restrict__ WH, const _Float16* __restrict__ WL,
    float* __restrict__ S) {
  constexpr int BK = 64;
  __shared__ _Float16 As[128 * BK];
  __shared__ _Float16 Bs[128 * BK];
  const int tid = threadIdx.x;
  const int wave = tid >> 6, lane = tid & 63;
  const long rowBase = (long)blockIdx.y * 128;
  const long colBase = (long)blockIdx.x * 128;
  const int srow = lane >> 3, scol = (lane & 7) * 8;
  const long aoff = (rowBase + wave * 32 + srow) * (long)D_MODEL + scol;
  const long boff = (colBase + wave * 32 + srow) * (long)D_MODEL + scol;
  _Float16* AsW = As + wave * 2048 + lane * 8;
  _Float16* BsW = Bs + wave * 2048 + lane * 8;
  const int wr = wave >> 1, wc = wave & 1;
  const int m16 = lane & 15, q = lane >> 4;

  floatx4 acc[4][4] = {};

  for (int t = 0; t < 48; t++) {
    const int seg = t >> 4;             // 0,1,2 (scalar-uniform)
    const int koff = (t & 15) * BK;     // 0..960
    const _Float16* Ag = ((seg == 1) ? XL : XH) + aoff + koff;
    const _Float16* Bg = ((seg == 2) ? WL : WH) + boff + koff;
#pragma unroll
    for (int i = 0; i < 4; i++) {
      gld_lds16(Ag + i * 8 * D_MODEL, AsW + i * 512);
      gld_lds16(Bg + i * 8 * D_MODEL, BsW + i * 512);
    }
    __syncthreads();
#pragma unroll
    for (int ks = 0; ks < 2; ks++) {
      half8 a[4], b[4];
#pragma unroll
      for (int mi = 0; mi < 4; mi++)
        a[mi] = *(const half8*)(As + (wr * 64 + mi * 16 + m16) * BK + ks * 32 + q * 8);
#pragma unroll
      for (int ni = 0; ni < 4; ni++)
        b[ni] = *(const half8*)(Bs + (wc * 64 + ni * 16 + m16) * BK + ks * 32 + q * 8);
#pragma unroll
      for (int mi = 0; mi < 4; mi++)
#pragma unroll
        for (int ni = 0; ni < 4; ni++)
          acc[mi][ni] = __builtin_amdgcn_mfma_f32_16x16x32_f16(
              a[mi], b[ni], acc[mi][ni], 0, 0, 0);
    }
    __syncthreads();
  }

  // C/D frag: col = lane&15, row = quad*4 + reg  [m89/m91 verified]
#pragma unroll
  for (int mi = 0; mi < 4; mi++)
#pragma unroll
    for (int r = 0; r < 4; r++) {
      const long rr = rowBase + wr * 64 + mi * 16 + q * 4 + r;
#pragma unroll
      for (int ni = 0; ni < 4; ni++)
        S[rr * D_FF + colBase + wc * 64 + ni * 16 + m16] = acc[mi][ni][r];
    }
}

// ---------------------------------------------------------------------------
// GEMM2: O[4096,1024] fp32 = P[4096,4096 (lda 8192)] @ WT[1024,4096]^T
// ---------------------------------------------------------------------------
__global__ __launch_bounds__(256, 2) void gemm2_kernel(
    const _Float16* __restrict__ P, const _Float16* __restrict__ WT,
    float* __restrict__ O) {
  constexpr int BK = 64, K = D_FF, LDA = 2 * D_FF;
  __shared__ _Float16 As[128 * BK];
  __shared__ _Float16 Bs[128 * BK];
  const int tid = threadIdx.x;
  const int wave = tid >> 6, lane = tid & 63;
  const long rowBase = (long)blockIdx.y * 128;
  const long colBase = (long)blockIdx.x * 128;
  const int srow = lane >> 3, scol = (lane & 7) * 8;
  const _Float16* Ag = P + (rowBase + wave * 32 + srow) * (long)LDA + scol;
  const _Float16* Bg = WT + (colBase + wave * 32 + srow) * (long)K + scol;
  _Float16* AsW = As + wave * 2048 + lane * 8;
  _Float16* BsW = Bs + wave * 2048 + lane * 8;
  const int wr = wave >> 1, wc = wave & 1;
  const int m16 = lane & 15, q = lane >> 4;

  floatx4 acc[4][4] = {};

  for (int kt = 0; kt < K; kt += BK) {
#pragma unroll
    for (int i = 0; i < 4; i++) {
      gld_lds16(Ag + (long)i * 8 * LDA + kt, AsW + i * 512);
      gld_lds16(Bg + (long)i * 8 * K + kt, BsW + i * 512);
    }
    __syncthreads();
#pragma unroll
    for (int ks = 0; ks < 2; ks++) {
      half8 a[4], b[4];
#pragma unroll
      for (int mi = 0; mi < 4; mi++)
        a[mi] = *(const half8*)(As + (wr * 64 + mi * 16 + m16) * BK + ks * 32 + q * 8);
#pragma unroll
      for (int ni = 0; ni < 4; ni++)
        b[ni] = *(const half8*)(Bs + (wc * 64 + ni * 16 + m16) * BK + ks * 32 + q * 8);
#pragma unroll
      for (int mi = 0; mi < 4; mi++)
#pragma unroll
        for (int ni = 0; ni < 4; ni++)
          acc[mi][ni] = __builtin_amdgcn_mfma_f32_16x16x32_f16(
              a[mi], b[ni], acc[mi][ni], 0, 0, 0);
    }
    __syncthreads();
  }

#pragma unroll
  for (int mi = 0; mi < 4; mi++)
#pragma unroll
    for (int r = 0; r < 4; r++) {
      const long rr = rowBase + wr * 64 + mi * 16 + q * 4 + r;
#pragma unroll
      for (int ni = 0; ni < 4; ni++)
        O[rr * D_MODEL + colBase + wc * 64 + ni * 16 + m16] = acc[mi][ni][r];
    }
}

// ---------------------------------------------------------------------------
// softmax over rows of 4096: fp32 S in, fp16 P out in-place at row start.
// One block per row, 16 elements/thread.
// ---------------------------------------------------------------------------
__global__ __launch_bounds__(256) void softmax_kernel(float* __restrict__ S) {
  float* s = S + (long)blockIdx.x * D_FF;
  const int t = threadIdx.x;
  const int lane = t & 63, wave = t >> 6;
  __shared__ float redm[4], redl[4];

  float v[16];
  float mx = -3.4e38f;
#pragma unroll
  for (int seg = 0; seg < 4; seg++) {
    const float4 f = *(const float4*)(s + seg * 1024 + t * 4);
    v[seg * 4 + 0] = f.x; v[seg * 4 + 1] = f.y;
    v[seg * 4 + 2] = f.z; v[seg * 4 + 3] = f.w;
  }
#pragma unroll
  for (int j = 0; j < 16; j++) mx = fmaxf(mx, v[j]);
#pragma unroll
  for (int off = 32; off >= 1; off >>= 1) mx = fmaxf(mx, __shfl_xor(mx, off));
  if (lane == 0) redm[wave] = mx;
  __syncthreads();
  const float m = fmaxf(fmaxf(redm[0], redm[1]), fmaxf(redm[2], redm[3]));

  float sum = 0.f;
#pragma unroll
  for (int j = 0; j < 16; j++) {
    v[j] = __expf(v[j] - m);
    sum += v[j];
  }
#pragma unroll
  for (int off = 32; off >= 1; off >>= 1) sum += __shfl_xor(sum, off);
  if (lane == 0) redl[wave] = sum;
  __syncthreads();
  const float inv = 1.f / (redl[0] + redl[1] + redl[2] + redl[3]);

  _Float16* p = (_Float16*)s;  // all reads of this row completed above
#pragma unroll
  for (int seg = 0; seg < 4; seg++) {
    half4 h;
#pragma unroll
    for (int j = 0; j < 4; j++) h[j] = (_Float16)(v[seg * 4 + j] * inv);
    *(half4*)(p + seg * 1024 + t * 4) = h;
  }
}

// ---------------------------------------------------------------------------
extern "C" void kernel_launch(void* const* d_in, const int* in_sizes, int n_in,
                              void* d_out, int out_size, void* d_ws, size_t ws_size,
                              hipStream_t stream) {
  const float* x = (const float*)d_in[0];  // [16384,1024] fp32
  const float* w = (const float*)d_in[1];  // [4096,1024] fp32
  float* out = (float*)d_out;              // [16384,1024] fp32

  // ws layout: xh 32Mi | xl 32Mi | wh 8Mi | wl 8Mi | wT 8Mi | S 64Mi = 152Mi
  const size_t NEED = 152ull << 20;
  if (ws_size < NEED) return;  // leaves zeros -> absmax 5.93e-2 signature

  char* ws = (char*)d_ws;
  _Float16* xh = (_Float16*)(ws);
  _Float16* xl = (_Float16*)(ws + (32ull << 20));
  _Float16* wh = (_Float16*)(ws + (64ull << 20));
  _Float16* wl = (_Float16*)(ws + (72ull << 20));
  _Float16* wT = (_Float16*)(ws + (80ull << 20));
  float*    S  = (float*)   (ws + (88ull << 20));

  hipLaunchKernelGGL(rmsnorm_split_kernel, dim3(M_ROWS / 4), dim3(256), 0,
                     stream, x, xh, xl);
  hipLaunchKernelGGL(rmsnorm_split_kernel, dim3(D_FF / 4), dim3(256), 0,
                     stream, w, wh, wl);
  hipLaunchKernelGGL(transpose_kernel, dim3(D_MODEL / 32, D_FF / 32), dim3(256),
                     0, stream, w, wT);

  for (int c = 0; c < M_ROWS / MC; c++) {
    const long ro = (long)c * MC;
    hipLaunchKernelGGL(gemm1_kernel, dim3(D_FF / 128, MC / 128), dim3(256), 0,
                       stream, xh + ro * D_MODEL, xl + ro * D_MODEL, wh, wl, S);
    hipLaunchKernelGGL(softmax_kernel, dim3(MC), dim3(256), 0, stream, S);
    hipLaunchKernelGGL(gemm2_kernel, dim3(D_MODEL / 128, MC / 128), dim3(256),
                       0, stream, (const _Float16*)S, wT, out + ro * D_MODEL);
  }
}

// Round 3
// 863.253 us; speedup vs baseline: 1.1573x; 1.1573x over previous
//
#include <hip/hip_runtime.h>
#include <hip/hip_fp16.h>

// ---------------------------------------------------------------------------
// VQFFN1: out = softmax(rmsnorm(x) @ rmsnorm(w)^T) @ w
//   x: [16384,1024] fp32   w: [4096,1024] fp32   out: [16384,1024] fp32
// fp32 scores (softmax is near-argmax); GEMM1 compensated fp16
// (S = xh*wh + xl*wh + xh*wl, K'=3072); GEMM2 plain fp16.
// R2: XOR-swizzled LDS layout in both GEMMs (kills 16-way bank aliasing on
// ds_read_b128; slot (row,k8) holds data (row, k8^(row&7)), applied by
// permuting the *global source* lane addresses so global_load_lds's
// lane-contiguous LDS dst constraint is preserved).
// ---------------------------------------------------------------------------

#define D_MODEL 1024
#define D_FF    4096
#define M_ROWS  16384
#define MC      4096

typedef _Float16 half8 __attribute__((ext_vector_type(8)));
typedef _Float16 half4 __attribute__((ext_vector_type(4)));
typedef float    floatx4 __attribute__((ext_vector_type(4)));

// async global->LDS, 16B/lane; LDS dst = wave-uniform base + lane*16 (m97)
__device__ __forceinline__ void gld_lds16(const void* g, void* l) {
  __builtin_amdgcn_global_load_lds(
      (const __attribute__((address_space(1))) void*)g,
      (__attribute__((address_space(3))) void*)l, 16, 0, 0);
}

// ---------------------------------------------------------------------------
// rmsnorm (fp32 in) + hi/lo fp16 split. One wave per row of 1024.
// ---------------------------------------------------------------------------
__global__ __launch_bounds__(256) void rmsnorm_split_kernel(
    const float* __restrict__ X, _Float16* __restrict__ XH,
    _Float16* __restrict__ XL) {
  const int lane = threadIdx.x & 63;
  const long row = (long)blockIdx.x * 4 + (threadIdx.x >> 6);
  const float* x = X + row * D_MODEL;
  float v[16];
  float ss = 0.f;
#pragma unroll
  for (int s = 0; s < 4; s++) {
    const float4 f = *(const float4*)(x + s * 256 + lane * 4);
    v[s * 4 + 0] = f.x; v[s * 4 + 1] = f.y;
    v[s * 4 + 2] = f.z; v[s * 4 + 3] = f.w;
    ss += f.x * f.x + f.y * f.y + f.z * f.z + f.w * f.w;
  }
#pragma unroll
  for (int off = 32; off >= 1; off >>= 1) ss += __shfl_xor(ss, off);
  const float inv = rsqrtf(ss * (1.0f / D_MODEL) + 1e-6f);
#pragma unroll
  for (int s = 0; s < 4; s++) {
    half4 h, l;
#pragma unroll
    for (int j = 0; j < 4; j++) {
      const float t = v[s * 4 + j] * inv;
      const _Float16 hi = (_Float16)t;
      h[j] = hi;
      l[j] = (_Float16)(t - (float)hi);
    }
    *(half4*)(XH + row * D_MODEL + s * 256 + lane * 4) = h;
    *(half4*)(XL + row * D_MODEL + s * 256 + lane * 4) = l;
  }
}

// ---------------------------------------------------------------------------
// transpose w [4096,1024] fp32 -> wT [1024,4096] fp16 (unnormalized, GEMM2 B)
// ---------------------------------------------------------------------------
__global__ __launch_bounds__(256) void transpose_kernel(
    const float* __restrict__ W, _Float16* __restrict__ WT) {
  __shared__ _Float16 tile[32][33];
  const int tx = threadIdx.x & 31;
  const int ty = threadIdx.x >> 5;  // 0..7
  const int d0 = blockIdx.x * 32;
  const int c0 = blockIdx.y * 32;
#pragma unroll
  for (int i = 0; i < 32; i += 8)
    tile[ty + i][tx] = (_Float16)W[(long)(c0 + ty + i) * D_MODEL + d0 + tx];
  __syncthreads();
#pragma unroll
  for (int i = 0; i < 32; i += 8)
    WT[(long)(d0 + ty + i) * D_FF + c0 + tx] = tile[tx][ty + i];
}

// ---------------------------------------------------------------------------
// Shared GEMM K-loop body pieces (m97 structure + XOR swizzle).
// LDS slot (row, k8s) holds global data (row, k8s ^ (row&7)).
// Staging lane L of instr i: row_local = i*8 + (L>>3), slot k8s = L&7
//   -> global col-block = (L&7) ^ (L>>3)   (row&7 == (L>>3)&7)
// Fragment read (row, k8=ks*4+q): LDS k8s = k8 ^ (m16&7)  (row&7 == m16&7)
// ---------------------------------------------------------------------------

// GEMM1 (compensated): S[4096,4096] fp32, 3 segments of K=1024.
__global__ __launch_bounds__(256, 2) void gemm1_kernel(
    const _Float16* __restrict__ XH, const _Float16* __restrict__ XL,
    const _Float16* __restrict__ WH, const _Float16* __restrict__ WL,
    float* __restrict__ S) {
  constexpr int BK = 64;
  __shared__ _Float16 As[128 * BK];
  __shared__ _Float16 Bs[128 * BK];
  const int tid = threadIdx.x;
  const int wave = tid >> 6, lane = tid & 63;
  const long rowBase = (long)blockIdx.y * 128;
  const long colBase = (long)blockIdx.x * 128;
  const int srow = lane >> 3;
  const int scol = ((lane & 7) ^ (lane >> 3)) * 8;  // XOR-swizzled source col
  const long aoff = (rowBase + wave * 32 + srow) * (long)D_MODEL + scol;
  const long boff = (colBase + wave * 32 + srow) * (long)D_MODEL + scol;
  _Float16* AsW = As + wave * 2048 + lane * 8;
  _Float16* BsW = Bs + wave * 2048 + lane * 8;
  const int wr = wave >> 1, wc = wave & 1;
  const int m16 = lane & 15, q = lane >> 4;
  const int mx7 = m16 & 7;

  floatx4 acc[4][4] = {};

  const _Float16* Asegs[3] = {XH + aoff, XL + aoff, XH + aoff};
  const _Float16* Bsegs[3] = {WH + boff, WH + boff, WL + boff};

#pragma unroll
  for (int seg = 0; seg < 3; seg++) {
    const _Float16* Ag = Asegs[seg];
    const _Float16* Bg = Bsegs[seg];
    for (int kt = 0; kt < D_MODEL; kt += BK) {
#pragma unroll
      for (int i = 0; i < 4; i++) {
        gld_lds16(Ag + i * 8 * D_MODEL + kt, AsW + i * 512);
        gld_lds16(Bg + i * 8 * D_MODEL + kt, BsW + i * 512);
      }
      __syncthreads();
#pragma unroll
      for (int ks = 0; ks < 2; ks++) {
        const int kx = ((ks * 4 + q) ^ mx7) * 8;  // swizzled k-offset (halves)
        half8 a[4], b[4];
#pragma unroll
        for (int mi = 0; mi < 4; mi++)
          a[mi] = *(const half8*)(As + (wr * 64 + mi * 16 + m16) * BK + kx);
#pragma unroll
        for (int ni = 0; ni < 4; ni++)
          b[ni] = *(const half8*)(Bs + (wc * 64 + ni * 16 + m16) * BK + kx);
#pragma unroll
        for (int mi = 0; mi < 4; mi++)
#pragma unroll
          for (int ni = 0; ni < 4; ni++)
            acc[mi][ni] = __builtin_amdgcn_mfma_f32_16x16x32_f16(
                a[mi], b[ni], acc[mi][ni], 0, 0, 0);
      }
      __syncthreads();
    }
  }

  // C/D frag: col = lane&15, row = quad*4 + reg  [m89/m91 verified]
#pragma unroll
  for (int mi = 0; mi < 4; mi++)
#pragma unroll
    for (int r = 0; r < 4; r++) {
      const long rr = rowBase + wr * 64 + mi * 16 + q * 4 + r;
#pragma unroll
      for (int ni = 0; ni < 4; ni++)
        S[rr * D_FF + colBase + wc * 64 + ni * 16 + m16] = acc[mi][ni][r];
    }
}

// GEMM2: O[4096,1024] fp32 = P[4096, lda 8192] @ WT[1024,4096]^T
__global__ __launch_bounds__(256, 2) void gemm2_kernel(
    const _Float16* __restrict__ P, const _Float16* __restrict__ WT,
    float* __restrict__ O) {
  constexpr int BK = 64, K = D_FF, LDA = 2 * D_FF;
  __shared__ _Float16 As[128 * BK];
  __shared__ _Float16 Bs[128 * BK];
  const int tid = threadIdx.x;
  const int wave = tid >> 6, lane = tid & 63;
  const long rowBase = (long)blockIdx.y * 128;
  const long colBase = (long)blockIdx.x * 128;
  const int srow = lane >> 3;
  const int scol = ((lane & 7) ^ (lane >> 3)) * 8;
  const _Float16* Ag = P + (rowBase + wave * 32 + srow) * (long)LDA + scol;
  const _Float16* Bg = WT + (colBase + wave * 32 + srow) * (long)K + scol;
  _Float16* AsW = As + wave * 2048 + lane * 8;
  _Float16* BsW = Bs + wave * 2048 + lane * 8;
  const int wr = wave >> 1, wc = wave & 1;
  const int m16 = lane & 15, q = lane >> 4;
  const int mx7 = m16 & 7;

  floatx4 acc[4][4] = {};

  for (int kt = 0; kt < K; kt += BK) {
#pragma unroll
    for (int i = 0; i < 4; i++) {
      gld_lds16(Ag + (long)i * 8 * LDA + kt, AsW + i * 512);
      gld_lds16(Bg + (long)i * 8 * K + kt, BsW + i * 512);
    }
    __syncthreads();
#pragma unroll
    for (int ks = 0; ks < 2; ks++) {
      const int kx = ((ks * 4 + q) ^ mx7) * 8;
      half8 a[4], b[4];
#pragma unroll
      for (int mi = 0; mi < 4; mi++)
        a[mi] = *(const half8*)(As + (wr * 64 + mi * 16 + m16) * BK + kx);
#pragma unroll
      for (int ni = 0; ni < 4; ni++)
        b[ni] = *(const half8*)(Bs + (wc * 64 + ni * 16 + m16) * BK + kx);
#pragma unroll
      for (int mi = 0; mi < 4; mi++)
#pragma unroll
        for (int ni = 0; ni < 4; ni++)
          acc[mi][ni] = __builtin_amdgcn_mfma_f32_16x16x32_f16(
              a[mi], b[ni], acc[mi][ni], 0, 0, 0);
    }
    __syncthreads();
  }

#pragma unroll
  for (int mi = 0; mi < 4; mi++)
#pragma unroll
    for (int r = 0; r < 4; r++) {
      const long rr = rowBase + wr * 64 + mi * 16 + q * 4 + r;
#pragma unroll
      for (int ni = 0; ni < 4; ni++)
        O[rr * D_MODEL + colBase + wc * 64 + ni * 16 + m16] = acc[mi][ni][r];
    }
}

// ---------------------------------------------------------------------------
// softmax over rows of 4096: fp32 S in, fp16 P out in-place at row start.
// ---------------------------------------------------------------------------
__global__ __launch_bounds__(256) void softmax_kernel(float* __restrict__ S) {
  float* s = S + (long)blockIdx.x * D_FF;
  const int t = threadIdx.x;
  const int lane = t & 63, wave = t >> 6;
  __shared__ float redm[4], redl[4];

  float v[16];
  float mx = -3.4e38f;
#pragma unroll
  for (int seg = 0; seg < 4; seg++) {
    const float4 f = *(const float4*)(s + seg * 1024 + t * 4);
    v[seg * 4 + 0] = f.x; v[seg * 4 + 1] = f.y;
    v[seg * 4 + 2] = f.z; v[seg * 4 + 3] = f.w;
  }
#pragma unroll
  for (int j = 0; j < 16; j++) mx = fmaxf(mx, v[j]);
#pragma unroll
  for (int off = 32; off >= 1; off >>= 1) mx = fmaxf(mx, __shfl_xor(mx, off));
  if (lane == 0) redm[wave] = mx;
  __syncthreads();
  const float m = fmaxf(fmaxf(redm[0], redm[1]), fmaxf(redm[2], redm[3]));

  float sum = 0.f;
#pragma unroll
  for (int j = 0; j < 16; j++) {
    v[j] = __expf(v[j] - m);
    sum += v[j];
  }
#pragma unroll
  for (int off = 32; off >= 1; off >>= 1) sum += __shfl_xor(sum, off);
  if (lane == 0) redl[wave] = sum;
  __syncthreads();
  const float inv = 1.f / (redl[0] + redl[1] + redl[2] + redl[3]);

  _Float16* p = (_Float16*)s;  // all reads of this row completed above
#pragma unroll
  for (int seg = 0; seg < 4; seg++) {
    half4 h;
#pragma unroll
    for (int j = 0; j < 4; j++) h[j] = (_Float16)(v[seg * 4 + j] * inv);
    *(half4*)(p + seg * 1024 + t * 4) = h;
  }
}

// ---------------------------------------------------------------------------
extern "C" void kernel_launch(void* const* d_in, const int* in_sizes, int n_in,
                              void* d_out, int out_size, void* d_ws, size_t ws_size,
                              hipStream_t stream) {
  const float* x = (const float*)d_in[0];  // [16384,1024] fp32
  const float* w = (const float*)d_in[1];  // [4096,1024] fp32
  float* out = (float*)d_out;              // [16384,1024] fp32

  // ws layout: xh 32Mi | xl 32Mi | wh 8Mi | wl 8Mi | wT 8Mi | S 64Mi = 152Mi
  const size_t NEED = 152ull << 20;
  if (ws_size < NEED) return;

  char* ws = (char*)d_ws;
  _Float16* xh = (_Float16*)(ws);
  _Float16* xl = (_Float16*)(ws + (32ull << 20));
  _Float16* wh = (_Float16*)(ws + (64ull << 20));
  _Float16* wl = (_Float16*)(ws + (72ull << 20));
  _Float16* wT = (_Float16*)(ws + (80ull << 20));
  float*    S  = (float*)   (ws + (88ull << 20));

  hipLaunchKernelGGL(rmsnorm_split_kernel, dim3(M_ROWS / 4), dim3(256), 0,
                     stream, x, xh, xl);
  hipLaunchKernelGGL(rmsnorm_split_kernel, dim3(D_FF / 4), dim3(256), 0,
                     stream, w, wh, wl);
  hipLaunchKernelGGL(transpose_kernel, dim3(D_MODEL / 32, D_FF / 32), dim3(256),
                     0, stream, w, wT);

  for (int c = 0; c < M_ROWS / MC; c++) {
    const long ro = (long)c * MC;
    hipLaunchKernelGGL(gemm1_kernel, dim3(D_FF / 128, MC / 128), dim3(256), 0,
                       stream, xh + ro * D_MODEL, xl + ro * D_MODEL, wh, wl, S);
    hipLaunchKernelGGL(softmax_kernel, dim3(MC), dim3(256), 0, stream, S);
    hipLaunchKernelGGL(gemm2_kernel, dim3(D_MODEL / 128, MC / 128), dim3(256),
                       0, stream, (const _Float16*)S, wT, out + ro * D_MODEL);
  }
}

// Round 4
// 854.701 us; speedup vs baseline: 1.1689x; 1.0100x over previous
//
#include <hip/hip_runtime.h>
#include <hip/hip_fp16.h>

// ---------------------------------------------------------------------------
// VQFFN1: out = softmax(rmsnorm(x) @ rmsnorm(w)^T) @ w
//   x: [16384,1024] fp32   w: [4096,1024] fp32   out: [16384,1024] fp32
// fp32 scores (softmax near-argmax); GEMM1 compensated fp16
// (S = xh*wh + xl*wh + xh*wl, K'=3072); GEMM2 plain fp16.
// R2: XOR-swizzled LDS (bank conflicts 3.8e7 -> 0; gemm1 ~1000 TF eff).
// R3: gemm2 split-K=2 + f32 HW atomics into zeroed d_out (grid 256->512
//     blocks = 2/CU, fixes the 1-block/CU occupancy hole); merged rmsnorms.
// ---------------------------------------------------------------------------

#define D_MODEL 1024
#define D_FF    4096
#define M_ROWS  16384
#define MC      4096

typedef _Float16 half8 __attribute__((ext_vector_type(8)));
typedef _Float16 half4 __attribute__((ext_vector_type(4)));
typedef float    floatx4 __attribute__((ext_vector_type(4)));

// async global->LDS, 16B/lane; LDS dst = wave-uniform base + lane*16 (m97)
__device__ __forceinline__ void gld_lds16(const void* g, void* l) {
  __builtin_amdgcn_global_load_lds(
      (const __attribute__((address_space(1))) void*)g,
      (__attribute__((address_space(3))) void*)l, 16, 0, 0);
}

// ---------------------------------------------------------------------------
// rmsnorm (fp32 in) + hi/lo fp16 split. One wave per row of 1024.
// Blocks [0, MB_X) -> x rows; blocks [MB_X, MB_X+MB_W) -> w rows.
// ---------------------------------------------------------------------------
#define MB_X (M_ROWS / 4)
#define MB_W (D_FF / 4)
__global__ __launch_bounds__(256) void rmsnorm_split_kernel(
    const float* __restrict__ X, _Float16* __restrict__ XH,
    _Float16* __restrict__ XL, const float* __restrict__ W,
    _Float16* __restrict__ WH, _Float16* __restrict__ WL) {
  const int lane = threadIdx.x & 63;
  const bool isW = blockIdx.x >= MB_X;
  const long row = (long)(isW ? blockIdx.x - MB_X : blockIdx.x) * 4 +
                   (threadIdx.x >> 6);
  const float* x = (isW ? W : X) + row * D_MODEL;
  _Float16* YH = (isW ? WH : XH) + row * D_MODEL;
  _Float16* YL = (isW ? WL : XL) + row * D_MODEL;

  float v[16];
  float ss = 0.f;
#pragma unroll
  for (int s = 0; s < 4; s++) {
    const float4 f = *(const float4*)(x + s * 256 + lane * 4);
    v[s * 4 + 0] = f.x; v[s * 4 + 1] = f.y;
    v[s * 4 + 2] = f.z; v[s * 4 + 3] = f.w;
    ss += f.x * f.x + f.y * f.y + f.z * f.z + f.w * f.w;
  }
#pragma unroll
  for (int off = 32; off >= 1; off >>= 1) ss += __shfl_xor(ss, off);
  const float inv = rsqrtf(ss * (1.0f / D_MODEL) + 1e-6f);
#pragma unroll
  for (int s = 0; s < 4; s++) {
    half4 h, l;
#pragma unroll
    for (int j = 0; j < 4; j++) {
      const float t = v[s * 4 + j] * inv;
      const _Float16 hi = (_Float16)t;
      h[j] = hi;
      l[j] = (_Float16)(t - (float)hi);
    }
    *(half4*)(YH + s * 256 + lane * 4) = h;
    *(half4*)(YL + s * 256 + lane * 4) = l;
  }
}

// ---------------------------------------------------------------------------
// transpose w [4096,1024] fp32 -> wT [1024,4096] fp16 (unnormalized, GEMM2 B)
// ---------------------------------------------------------------------------
__global__ __launch_bounds__(256) void transpose_kernel(
    const float* __restrict__ W, _Float16* __restrict__ WT) {
  __shared__ _Float16 tile[32][33];
  const int tx = threadIdx.x & 31;
  const int ty = threadIdx.x >> 5;  // 0..7
  const int d0 = blockIdx.x * 32;
  const int c0 = blockIdx.y * 32;
#pragma unroll
  for (int i = 0; i < 32; i += 8)
    tile[ty + i][tx] = (_Float16)W[(long)(c0 + ty + i) * D_MODEL + d0 + tx];
  __syncthreads();
#pragma unroll
  for (int i = 0; i < 32; i += 8)
    WT[(long)(d0 + ty + i) * D_FF + c0 + tx] = tile[tx][ty + i];
}

// ---------------------------------------------------------------------------
// GEMM K-loop (m97 structure + XOR swizzle).
// LDS slot (row, k8s) holds global data (row, k8s ^ (row&7)); swizzle applied
// by permuting the *global source* lane address (scol), preserving
// global_load_lds's lane-contiguous LDS dst. Fragment read XORs with m16&7.
// ---------------------------------------------------------------------------

// GEMM1 (compensated): S[4096,4096] fp32, 3 segments of K=1024.
__global__ __launch_bounds__(256, 2) void gemm1_kernel(
    const _Float16* __restrict__ XH, const _Float16* __restrict__ XL,
    const _Float16* __restrict__ WH, const _Float16* __restrict__ WL,
    float* __restrict__ S) {
  constexpr int BK = 64;
  __shared__ _Float16 As[128 * BK];
  __shared__ _Float16 Bs[128 * BK];
  const int tid = threadIdx.x;
  const int wave = tid >> 6, lane = tid & 63;
  const long rowBase = (long)blockIdx.y * 128;
  const long colBase = (long)blockIdx.x * 128;
  const int srow = lane >> 3;
  const int scol = ((lane & 7) ^ (lane >> 3)) * 8;  // XOR-swizzled source col
  const long aoff = (rowBase + wave * 32 + srow) * (long)D_MODEL + scol;
  const long boff = (colBase + wave * 32 + srow) * (long)D_MODEL + scol;
  _Float16* AsW = As + wave * 2048 + lane * 8;
  _Float16* BsW = Bs + wave * 2048 + lane * 8;
  const int wr = wave >> 1, wc = wave & 1;
  const int m16 = lane & 15, q = lane >> 4;
  const int mx7 = m16 & 7;

  floatx4 acc[4][4] = {};

  const _Float16* Asegs[3] = {XH + aoff, XL + aoff, XH + aoff};
  const _Float16* Bsegs[3] = {WH + boff, WH + boff, WL + boff};

#pragma unroll
  for (int seg = 0; seg < 3; seg++) {
    const _Float16* Ag = Asegs[seg];
    const _Float16* Bg = Bsegs[seg];
    for (int kt = 0; kt < D_MODEL; kt += BK) {
#pragma unroll
      for (int i = 0; i < 4; i++) {
        gld_lds16(Ag + i * 8 * D_MODEL + kt, AsW + i * 512);
        gld_lds16(Bg + i * 8 * D_MODEL + kt, BsW + i * 512);
      }
      __syncthreads();
#pragma unroll
      for (int ks = 0; ks < 2; ks++) {
        const int kx = ((ks * 4 + q) ^ mx7) * 8;  // swizzled k-offset (halves)
        half8 a[4], b[4];
#pragma unroll
        for (int mi = 0; mi < 4; mi++)
          a[mi] = *(const half8*)(As + (wr * 64 + mi * 16 + m16) * BK + kx);
#pragma unroll
        for (int ni = 0; ni < 4; ni++)
          b[ni] = *(const half8*)(Bs + (wc * 64 + ni * 16 + m16) * BK + kx);
#pragma unroll
        for (int mi = 0; mi < 4; mi++)
#pragma unroll
          for (int ni = 0; ni < 4; ni++)
            acc[mi][ni] = __builtin_amdgcn_mfma_f32_16x16x32_f16(
                a[mi], b[ni], acc[mi][ni], 0, 0, 0);
      }
      __syncthreads();
    }
  }

  // C/D frag: col = lane&15, row = quad*4 + reg  [m89/m91 verified]
#pragma unroll
  for (int mi = 0; mi < 4; mi++)
#pragma unroll
    for (int r = 0; r < 4; r++) {
      const long rr = rowBase + wr * 64 + mi * 16 + q * 4 + r;
#pragma unroll
      for (int ni = 0; ni < 4; ni++)
        S[rr * D_FF + colBase + wc * 64 + ni * 16 + m16] = acc[mi][ni][r];
    }
}

// GEMM2: O[4096,1024] fp32 += P[4096, lda 8192] @ WT[1024,4096]^T
// split-K=2 (blockIdx.z), HW f32 atomics into pre-zeroed O.
__global__ __launch_bounds__(256, 2) void gemm2_kernel(
    const _Float16* __restrict__ P, const _Float16* __restrict__ WT,
    float* __restrict__ O) {
  constexpr int BK = 64, K = D_FF, LDA = 2 * D_FF, KSPLIT = 2048;
  __shared__ _Float16 As[128 * BK];
  __shared__ _Float16 Bs[128 * BK];
  const int tid = threadIdx.x;
  const int wave = tid >> 6, lane = tid & 63;
  const long rowBase = (long)blockIdx.y * 128;
  const long colBase = (long)blockIdx.x * 128;
  const int k0 = blockIdx.z * KSPLIT;
  const int srow = lane >> 3;
  const int scol = ((lane & 7) ^ (lane >> 3)) * 8;
  const _Float16* Ag = P + (rowBase + wave * 32 + srow) * (long)LDA + scol;
  const _Float16* Bg = WT + (colBase + wave * 32 + srow) * (long)K + scol;
  _Float16* AsW = As + wave * 2048 + lane * 8;
  _Float16* BsW = Bs + wave * 2048 + lane * 8;
  const int wr = wave >> 1, wc = wave & 1;
  const int m16 = lane & 15, q = lane >> 4;
  const int mx7 = m16 & 7;

  floatx4 acc[4][4] = {};

  for (int kt = k0; kt < k0 + KSPLIT; kt += BK) {
#pragma unroll
    for (int i = 0; i < 4; i++) {
      gld_lds16(Ag + (long)i * 8 * LDA + kt, AsW + i * 512);
      gld_lds16(Bg + (long)i * 8 * K + kt, BsW + i * 512);
    }
    __syncthreads();
#pragma unroll
    for (int ks = 0; ks < 2; ks++) {
      const int kx = ((ks * 4 + q) ^ mx7) * 8;
      half8 a[4], b[4];
#pragma unroll
      for (int mi = 0; mi < 4; mi++)
        a[mi] = *(const half8*)(As + (wr * 64 + mi * 16 + m16) * BK + kx);
#pragma unroll
      for (int ni = 0; ni < 4; ni++)
        b[ni] = *(const half8*)(Bs + (wc * 64 + ni * 16 + m16) * BK + kx);
#pragma unroll
      for (int mi = 0; mi < 4; mi++)
#pragma unroll
        for (int ni = 0; ni < 4; ni++)
          acc[mi][ni] = __builtin_amdgcn_mfma_f32_16x16x32_f16(
              a[mi], b[ni], acc[mi][ni], 0, 0, 0);
    }
    __syncthreads();
  }

#pragma unroll
  for (int mi = 0; mi < 4; mi++)
#pragma unroll
    for (int r = 0; r < 4; r++) {
      const long rr = rowBase + wr * 64 + mi * 16 + q * 4 + r;
#pragma unroll
      for (int ni = 0; ni < 4; ni++)
        unsafeAtomicAdd(&O[rr * D_MODEL + colBase + wc * 64 + ni * 16 + m16],
                        acc[mi][ni][r]);
    }
}

// ---------------------------------------------------------------------------
// softmax over rows of 4096: fp32 S in, fp16 P out in-place at row start.
// ---------------------------------------------------------------------------
__global__ __launch_bounds__(256) void softmax_kernel(float* __restrict__ S) {
  float* s = S + (long)blockIdx.x * D_FF;
  const int t = threadIdx.x;
  const int lane = t & 63, wave = t >> 6;
  __shared__ float redm[4], redl[4];

  float v[16];
  float mx = -3.4e38f;
#pragma unroll
  for (int seg = 0; seg < 4; seg++) {
    const float4 f = *(const float4*)(s + seg * 1024 + t * 4);
    v[seg * 4 + 0] = f.x; v[seg * 4 + 1] = f.y;
    v[seg * 4 + 2] = f.z; v[seg * 4 + 3] = f.w;
  }
#pragma unroll
  for (int j = 0; j < 16; j++) mx = fmaxf(mx, v[j]);
#pragma unroll
  for (int off = 32; off >= 1; off >>= 1) mx = fmaxf(mx, __shfl_xor(mx, off));
  if (lane == 0) redm[wave] = mx;
  __syncthreads();
  const float m = fmaxf(fmaxf(redm[0], redm[1]), fmaxf(redm[2], redm[3]));

  float sum = 0.f;
#pragma unroll
  for (int j = 0; j < 16; j++) {
    v[j] = __expf(v[j] - m);
    sum += v[j];
  }
#pragma unroll
  for (int off = 32; off >= 1; off >>= 1) sum += __shfl_xor(sum, off);
  if (lane == 0) redl[wave] = sum;
  __syncthreads();
  const float inv = 1.f / (redl[0] + redl[1] + redl[2] + redl[3]);

  _Float16* p = (_Float16*)s;  // all reads of this row completed above
#pragma unroll
  for (int seg = 0; seg < 4; seg++) {
    half4 h;
#pragma unroll
    for (int j = 0; j < 4; j++) h[j] = (_Float16)(v[seg * 4 + j] * inv);
    *(half4*)(p + seg * 1024 + t * 4) = h;
  }
}

// ---------------------------------------------------------------------------
extern "C" void kernel_launch(void* const* d_in, const int* in_sizes, int n_in,
                              void* d_out, int out_size, void* d_ws, size_t ws_size,
                              hipStream_t stream) {
  const float* x = (const float*)d_in[0];  // [16384,1024] fp32
  const float* w = (const float*)d_in[1];  // [4096,1024] fp32
  float* out = (float*)d_out;              // [16384,1024] fp32

  // ws layout: xh 32Mi | xl 32Mi | wh 8Mi | wl 8Mi | wT 8Mi | S 64Mi = 152Mi
  const size_t NEED = 152ull << 20;
  if (ws_size < NEED) return;

  char* ws = (char*)d_ws;
  _Float16* xh = (_Float16*)(ws);
  _Float16* xl = (_Float16*)(ws + (32ull << 20));
  _Float16* wh = (_Float16*)(ws + (64ull << 20));
  _Float16* wl = (_Float16*)(ws + (72ull << 20));
  _Float16* wT = (_Float16*)(ws + (80ull << 20));
  float*    S  = (float*)   (ws + (88ull << 20));

  // gemm2 accumulates via atomics -> zero d_out first (graph-capture safe)
  hipMemsetAsync(d_out, 0, (size_t)M_ROWS * D_MODEL * sizeof(float), stream);

  hipLaunchKernelGGL(rmsnorm_split_kernel, dim3(MB_X + MB_W), dim3(256), 0,
                     stream, x, xh, xl, w, wh, wl);
  hipLaunchKernelGGL(transpose_kernel, dim3(D_MODEL / 32, D_FF / 32), dim3(256),
                     0, stream, w, wT);

  for (int c = 0; c < M_ROWS / MC; c++) {
    const long ro = (long)c * MC;
    hipLaunchKernelGGL(gemm1_kernel, dim3(D_FF / 128, MC / 128), dim3(256), 0,
                       stream, xh + ro * D_MODEL, xl + ro * D_MODEL, wh, wl, S);
    hipLaunchKernelGGL(softmax_kernel, dim3(MC), dim3(256), 0, stream, S);
    hipLaunchKernelGGL(gemm2_kernel, dim3(D_MODEL / 128, MC / 128, 2),
                       dim3(256), 0, stream, (const _Float16*)S, wT,
                       out + ro * D_MODEL);
  }
}